// Round 7
// baseline (1928.042 us; speedup 1.0000x reference)
//
#include <hip/hip_runtime.h>
#include <hip/hip_bf16.h>

// DeRA forward: x @ Wd^T -> qkv+rope -> attn -> (o @ (Wup*Wo)^T + Wup*bo)
// Shapes fixed: seq=12480 = 8 frames x (30*52=1560), DIM=3072, RANK=192, 4 heads x 48.

#define DIM 3072
#define RANK 192
#define NH 4
#define HD 48
#define CP 24           // pairs per head
#define TT 8
#define GW 52
#define SF 1560
#define SEQ 12480

typedef float f32x4 __attribute__((ext_vector_type(4)));
typedef short bf16x8 __attribute__((ext_vector_type(8)));

static __device__ __forceinline__ unsigned short f2bf(float f) {
    union { float f; unsigned int u; } v; v.f = f;
    unsigned int u = v.u;
    return (unsigned short)((u + 0x7FFFu + ((u >> 16) & 1u)) >> 16);  // RNE
}
static __device__ __forceinline__ ushort4 cvt4(float4 v) {
    ushort4 o; o.x = f2bf(v.x); o.y = f2bf(v.y); o.z = f2bf(v.z); o.w = f2bf(v.w);
    return o;
}

// ---------------- prep: Wc = Wup @ Wo (bf16), bc = Wup @ bo ----------------
__global__ __launch_bounds__(256) void prep_combine(
        const float* __restrict__ Wup, const float* __restrict__ Wo,
        const float* __restrict__ bo, unsigned short* __restrict__ Wcbf,
        float* __restrict__ bc) {
    int idx = blockIdx.x * 256 + threadIdx.x;
    if (idx >= DIM * RANK) return;
    int i = idx / RANK, j = idx % RANK;
    float s = 0.f;
    #pragma unroll 8
    for (int r = 0; r < RANK; ++r) s += Wup[i * RANK + r] * Wo[r * RANK + j];
    Wcbf[idx] = f2bf(s);
    if (j == 0) {
        float t = 0.f;
        for (int r = 0; r < RANK; ++r) t += Wup[i * RANK + r] * bo[r];
        bc[i] = t;
    }
}

__global__ __launch_bounds__(256) void prep_cvt(
        const float* __restrict__ src, unsigned short* __restrict__ dst, int n4) {
    int idx = blockIdx.x * 256 + threadIdx.x;
    if (idx >= n4) return;
    float4 v = reinterpret_cast<const float4*>(src)[idx];
    reinterpret_cast<ushort4*>(dst)[idx] = cvt4(v);
}

// ---------------- K1: XL = X @ Wd^T  (bf16 MFMA) ----------------
// BM=64 BN=64 BK=64, 4 waves 2x2, wave tile 32x32
#define K1_LDA 72   // 64 + 8 pad bf16 -> row stride 144B (16B-aligned, ~2-way banks)
__global__ __launch_bounds__(256) void k1_down(
        const float* __restrict__ X, const unsigned short* __restrict__ Wd,
        float* __restrict__ XL) {
    __shared__ unsigned short As[64][K1_LDA];
    __shared__ unsigned short Bs[64][K1_LDA];
    int m0 = blockIdx.x * 64, n0 = blockIdx.y * 64;
    int tid = threadIdx.x;
    int lane = tid & 63, wv = tid >> 6;
    int wm = wv >> 1, wn = wv & 1;
    f32x4 acc[2][2] = {};
    for (int k0 = 0; k0 < DIM; k0 += 64) {
        #pragma unroll
        for (int i = 0; i < 4; ++i) {          // A: 64x64 f32 -> bf16
            int q = tid + 256 * i;
            int row = q >> 4, c = (q & 15) * 4;
            float4 v = *reinterpret_cast<const float4*>(&X[(size_t)(m0 + row) * DIM + k0 + c]);
            *reinterpret_cast<ushort4*>(&As[row][c]) = cvt4(v);
        }
        #pragma unroll
        for (int i = 0; i < 2; ++i) {          // B: 64x64 bf16 = 512 int4 loads
            int q = tid + 256 * i;
            int row = q >> 3, c = (q & 7) * 8;
            *reinterpret_cast<int4*>(&Bs[row][c]) =
                *reinterpret_cast<const int4*>(&Wd[(size_t)(n0 + row) * DIM + k0 + c]);
        }
        __syncthreads();
        #pragma unroll
        for (int kk = 0; kk < 64; kk += 32) {
            int kof = kk + (lane >> 4) * 8;
            bf16x8 a[2], b[2];
            #pragma unroll
            for (int i = 0; i < 2; ++i)
                a[i] = *reinterpret_cast<const bf16x8*>(&As[wm * 32 + i * 16 + (lane & 15)][kof]);
            #pragma unroll
            for (int j = 0; j < 2; ++j)
                b[j] = *reinterpret_cast<const bf16x8*>(&Bs[wn * 32 + j * 16 + (lane & 15)][kof]);
            #pragma unroll
            for (int i = 0; i < 2; ++i)
                #pragma unroll
                for (int j = 0; j < 2; ++j)
                    acc[i][j] = __builtin_amdgcn_mfma_f32_16x16x32_bf16(a[i], b[j], acc[i][j], 0, 0, 0);
        }
        __syncthreads();
    }
    #pragma unroll
    for (int i = 0; i < 2; ++i)
        #pragma unroll
        for (int j = 0; j < 2; ++j)
            #pragma unroll
            for (int r = 0; r < 4; ++r) {
                int row = m0 + wm * 32 + i * 16 + (lane >> 4) * 4 + r;
                int col = n0 + wn * 32 + j * 16 + (lane & 15);
                XL[(size_t)row * RANK + col] = acc[i][j][r];
            }
}

// ---------------- K2: QKV + bias + RoPE (f32 VALU) ----------------
// 32 positions/block; threads = (pos 32) x (group 8); each thread 36 output pairs.
__global__ __launch_bounds__(256) void k2_qkv(
        const float* __restrict__ XL,
        const float* __restrict__ Wq, const float* __restrict__ bq,
        const float* __restrict__ Wk, const float* __restrict__ bk,
        const float* __restrict__ Wv, const float* __restrict__ bv,
        const float* __restrict__ fcos, const float* __restrict__ fsin,
        float* __restrict__ Q, float* __restrict__ Kb, float* __restrict__ Vb) {
    __shared__ float Xs[32][196];   // pad to 196: row stride %32 = 4 dwords -> conflict-free
    int p0 = blockIdx.x * 32;
    int tid = threadIdx.x;
    #pragma unroll
    for (int i = 0; i < 6; ++i) {
        int q = tid + 256 * i;                 // 1536 float4 = 32*48
        int row = q / 48, c = (q % 48) * 4;
        *reinterpret_cast<float4*>(&Xs[row][c]) =
            *reinterpret_cast<const float4*>(&XL[(size_t)(p0 + row) * RANK + c]);
    }
    __syncthreads();
    int pl = tid >> 3, g = tid & 7;
    int pos = p0 + pl;
    int f = pos / SF, pf = pos % SF;
    int hh = pf / GW, ww = pf % GW;
    for (int it = 0; it < 36; ++it) {
        int u = g + 8 * it;                    // 0..287
        int mat = u / 96;
        int pr = u % 96;
        int head = pr / CP, pp = pr % CP;
        const float* W = (mat == 0) ? Wq : (mat == 1) ? Wk : Wv;
        const float* b = (mat == 0) ? bq : (mat == 1) ? bk : bv;
        int row0 = head * HD + 2 * pp;
        float e0 = b[row0], e1 = b[row0 + 1];
        const float* w0 = &W[(size_t)row0 * RANK];
        const float* w1 = w0 + RANK;
        #pragma unroll 8
        for (int j = 0; j < RANK; j += 4) {
            float4 xv = *reinterpret_cast<const float4*>(&Xs[pl][j]);
            float4 a0 = *reinterpret_cast<const float4*>(&w0[j]);
            float4 a1 = *reinterpret_cast<const float4*>(&w1[j]);
            e0 += xv.x * a0.x + xv.y * a0.y + xv.z * a0.z + xv.w * a0.w;
            e1 += xv.x * a1.x + xv.y * a1.y + xv.z * a1.z + xv.w * a1.w;
        }
        float oa = e0, ob = e1;
        if (mat < 2 && pp >= 8) {
            int idx = (pp < 16) ? hh : ww;     // h-freqs then w-freqs, col = pp
            float cc = fcos[idx * CP + pp];
            float ss = fsin[idx * CP + pp];
            oa = e0 * cc - e1 * ss;
            ob = e0 * ss + e1 * cc;
        }
        float* dst = (mat == 0) ? Q : (mat == 1) ? Kb : Vb;
        size_t base = (((size_t)(f * NH + head)) * SF + pf) * HD + 2 * pp;
        dst[base] = oa; dst[base + 1] = ob;
    }
}

// ---------------- K3: flash attention, f32 VALU ----------------
// grid (qtile 25, head 4, frame 8), 256 thr: r4 = tid/16 (4 q-rows), c4 = tid%16.
// score cols per thread: c4 + 16*j  (keeps K-tile LDS reads ~2-way)
__global__ __launch_bounds__(256) void k3_attn(
        const float* __restrict__ Q, const float* __restrict__ Kb,
        const float* __restrict__ Vb, float* __restrict__ O) {
    __shared__ float Qs[64][52];
    __shared__ float Ks[64][52];
    __shared__ float Vs[64][52];
    __shared__ float Pt[64][68];   // P transposed: [k][q-row]
    int qt = blockIdx.x, n = blockIdx.y, f = blockIdx.z;
    size_t hbase = ((size_t)(f * NH + n)) * SF * HD;
    int q0 = qt * 64;
    int tid = threadIdx.x;
    int r4 = tid >> 4, c4 = tid & 15;
    const float scale = 0.14433756729740643f;  // 48^-0.5
    #pragma unroll
    for (int i = 0; i < 3; ++i) {              // stage Q (scaled)
        int q = tid + 256 * i;
        int row = q / 12, c = (q % 12) * 4;
        float4 v = {0.f, 0.f, 0.f, 0.f};
        if (q0 + row < SF)
            v = *reinterpret_cast<const float4*>(&Q[hbase + (size_t)(q0 + row) * HD + c]);
        v.x *= scale; v.y *= scale; v.z *= scale; v.w *= scale;
        *reinterpret_cast<float4*>(&Qs[row][c]) = v;
    }
    float Oa[4][3] = {};
    float mrow[4] = {-1e30f, -1e30f, -1e30f, -1e30f};
    float lrow[4] = {0.f, 0.f, 0.f, 0.f};
    for (int kt = 0; kt < 25; ++kt) {
        int kbase = kt * 64;
        __syncthreads();                       // prev PV done (and Q staged, iter 0)
        #pragma unroll
        for (int i = 0; i < 3; ++i) {          // stage K,V
            int q = tid + 256 * i;
            int row = q / 12, c = (q % 12) * 4;
            float4 kv = {0.f, 0.f, 0.f, 0.f}, vv = {0.f, 0.f, 0.f, 0.f};
            if (kbase + row < SF) {
                kv = *reinterpret_cast<const float4*>(&Kb[hbase + (size_t)(kbase + row) * HD + c]);
                vv = *reinterpret_cast<const float4*>(&Vb[hbase + (size_t)(kbase + row) * HD + c]);
            }
            *reinterpret_cast<float4*>(&Ks[row][c]) = kv;
            *reinterpret_cast<float4*>(&Vs[row][c]) = vv;
        }
        __syncthreads();
        float S[4][4] = {};
        #pragma unroll
        for (int kk = 0; kk < HD; kk += 4) {
            float4 qv[4], kv[4];
            #pragma unroll
            for (int i = 0; i < 4; ++i) qv[i] = *reinterpret_cast<const float4*>(&Qs[r4 * 4 + i][kk]);
            #pragma unroll
            for (int j = 0; j < 4; ++j) kv[j] = *reinterpret_cast<const float4*>(&Ks[c4 + 16 * j][kk]);
            #pragma unroll
            for (int i = 0; i < 4; ++i)
                #pragma unroll
                for (int j = 0; j < 4; ++j)
                    S[i][j] += qv[i].x * kv[j].x + qv[i].y * kv[j].y
                             + qv[i].z * kv[j].z + qv[i].w * kv[j].w;
        }
        #pragma unroll
        for (int j = 0; j < 4; ++j)
            if (kbase + c4 + 16 * j >= SF) {
                S[0][j] = -1e30f; S[1][j] = -1e30f; S[2][j] = -1e30f; S[3][j] = -1e30f;
            }
        #pragma unroll
        for (int i = 0; i < 4; ++i) {
            float mx = fmaxf(fmaxf(S[i][0], S[i][1]), fmaxf(S[i][2], S[i][3]));
            #pragma unroll
            for (int d = 1; d < 16; d <<= 1) mx = fmaxf(mx, __shfl_xor(mx, d));
            float mn = fmaxf(mrow[i], mx);
            float alpha = __expf(mrow[i] - mn);
            float rs = 0.f;
            #pragma unroll
            for (int j = 0; j < 4; ++j) { S[i][j] = __expf(S[i][j] - mn); rs += S[i][j]; }
            #pragma unroll
            for (int d = 1; d < 16; d <<= 1) rs += __shfl_xor(rs, d);
            lrow[i] = lrow[i] * alpha + rs;
            mrow[i] = mn;
            Oa[i][0] *= alpha; Oa[i][1] *= alpha; Oa[i][2] *= alpha;
        }
        #pragma unroll
        for (int j = 0; j < 4; ++j) {
            float4 pv; pv.x = S[0][j]; pv.y = S[1][j]; pv.z = S[2][j]; pv.w = S[3][j];
            *reinterpret_cast<float4*>(&Pt[c4 + 16 * j][r4 * 4]) = pv;
        }
        __syncthreads();
        int vc = c4 * 3;
        #pragma unroll 8
        for (int k = 0; k < 64; ++k) {
            float4 pv = *reinterpret_cast<const float4*>(&Pt[k][r4 * 4]);
            float v0 = Vs[k][vc], v1 = Vs[k][vc + 1], v2 = Vs[k][vc + 2];
            Oa[0][0] += pv.x * v0; Oa[0][1] += pv.x * v1; Oa[0][2] += pv.x * v2;
            Oa[1][0] += pv.y * v0; Oa[1][1] += pv.y * v1; Oa[1][2] += pv.y * v2;
            Oa[2][0] += pv.z * v0; Oa[2][1] += pv.z * v1; Oa[2][2] += pv.z * v2;
            Oa[3][0] += pv.w * v0; Oa[3][1] += pv.w * v1; Oa[3][2] += pv.w * v2;
        }
    }
    #pragma unroll
    for (int i = 0; i < 4; ++i) {
        int row = q0 + r4 * 4 + i;
        if (row < SF) {
            float inv = 1.0f / lrow[i];
            size_t ob = ((size_t)(f * SF + row)) * RANK + n * HD + c4 * 3;
            O[ob] = Oa[i][0] * inv; O[ob + 1] = Oa[i][1] * inv; O[ob + 2] = Oa[i][2] * inv;
        }
    }
}

// ---------------- K4: out = O @ Wc^T + bc  (bf16 MFMA) ----------------
// BM=64 BN=128, K=192 fully staged; 4 waves 2x2, wave tile 32x64
#define K4_LD 200   // 192 + 8 pad bf16 -> 400B stride (16B aligned)
__global__ __launch_bounds__(256) void k4_out(
        const float* __restrict__ O, const unsigned short* __restrict__ Wc,
        const float* __restrict__ bc, float* __restrict__ out) {
    __shared__ unsigned short As[64][K4_LD];
    __shared__ unsigned short Bs[128][K4_LD];
    int m0 = blockIdx.x * 64, n0 = blockIdx.y * 128;
    int tid = threadIdx.x, lane = tid & 63, wv = tid >> 6;
    int wm = wv >> 1, wn = wv & 1;
    #pragma unroll
    for (int i = 0; i < 12; ++i) {             // A: 64x192 f32 -> bf16 (3072 float4)
        int q = tid + 256 * i;
        int row = q / 48, c = (q % 48) * 4;
        float4 v = *reinterpret_cast<const float4*>(&O[(size_t)(m0 + row) * RANK + c]);
        *reinterpret_cast<ushort4*>(&As[row][c]) = cvt4(v);
    }
    #pragma unroll
    for (int i = 0; i < 12; ++i) {             // B: 128x192 bf16 = 3072 int4 loads
        int q = tid + 256 * i;
        int row = q / 24, c = (q % 24) * 8;
        *reinterpret_cast<int4*>(&Bs[row][c]) =
            *reinterpret_cast<const int4*>(&Wc[(size_t)(n0 + row) * RANK + c]);
    }
    __syncthreads();
    f32x4 acc[2][4] = {};
    #pragma unroll
    for (int kk = 0; kk < RANK; kk += 32) {
        int kof = kk + (lane >> 4) * 8;
        bf16x8 a[2], b[4];
        #pragma unroll
        for (int i = 0; i < 2; ++i)
            a[i] = *reinterpret_cast<const bf16x8*>(&As[wm * 32 + i * 16 + (lane & 15)][kof]);
        #pragma unroll
        for (int j = 0; j < 4; ++j)
            b[j] = *reinterpret_cast<const bf16x8*>(&Bs[wn * 64 + j * 16 + (lane & 15)][kof]);
        #pragma unroll
        for (int i = 0; i < 2; ++i)
            #pragma unroll
            for (int j = 0; j < 4; ++j)
                acc[i][j] = __builtin_amdgcn_mfma_f32_16x16x32_bf16(a[i], b[j], acc[i][j], 0, 0, 0);
    }
    #pragma unroll
    for (int i = 0; i < 2; ++i)
        #pragma unroll
        for (int j = 0; j < 4; ++j) {
            int col = n0 + wn * 64 + j * 16 + (lane & 15);
            float bias = bc[col];
            #pragma unroll
            for (int r = 0; r < 4; ++r) {
                int row = m0 + wm * 32 + i * 16 + (lane >> 4) * 4 + r;
                out[(size_t)row * DIM + col] = acc[i][j][r] + bias;
            }
        }
}

extern "C" void kernel_launch(void* const* d_in, const int* in_sizes, int n_in,
                              void* d_out, int out_size, void* d_ws, size_t ws_size,
                              hipStream_t stream) {
    (void)in_sizes; (void)n_in; (void)out_size; (void)ws_size;
    const float* x    = (const float*)d_in[0];
    const float* fcos = (const float*)d_in[6];
    const float* fsin = (const float*)d_in[7];
    const float* Wd   = (const float*)d_in[8];
    const float* Wup  = (const float*)d_in[9];
    const float* Wq   = (const float*)d_in[10];
    const float* bq   = (const float*)d_in[11];
    const float* Wk   = (const float*)d_in[12];
    const float* bk   = (const float*)d_in[13];
    const float* Wv   = (const float*)d_in[14];
    const float* bv   = (const float*)d_in[15];
    const float* Wo   = (const float*)d_in[16];
    const float* bo   = (const float*)d_in[17];
    float* out = (float*)d_out;

    char* ws = (char*)d_ws;
    size_t off = 0;
    auto alloc = [&](size_t bytes) {
        char* p = ws + off;
        off += (bytes + 255) & ~(size_t)255;
        return p;
    };
    float* XL  = (float*)alloc((size_t)SEQ * RANK * 4);
    float* Qb  = (float*)alloc((size_t)SEQ * RANK * 4);
    float* Kb  = (float*)alloc((size_t)SEQ * RANK * 4);
    float* Vb  = (float*)alloc((size_t)SEQ * RANK * 4);
    float* Ob  = (float*)alloc((size_t)SEQ * RANK * 4);
    unsigned short* Wdbf = (unsigned short*)alloc((size_t)RANK * DIM * 2);
    unsigned short* Wcbf = (unsigned short*)alloc((size_t)DIM * RANK * 2);
    float* bc = (float*)alloc((size_t)DIM * 4);

    prep_combine<<<(DIM * RANK + 255) / 256, 256, 0, stream>>>(Wup, Wo, bo, Wcbf, bc);
    prep_cvt<<<(RANK * DIM / 4 + 255) / 256, 256, 0, stream>>>(Wd, Wdbf, RANK * DIM / 4);
    k1_down<<<dim3(SEQ / 64, RANK / 64), 256, 0, stream>>>(x, Wdbf, XL);
    k2_qkv<<<SEQ / 32, 256, 0, stream>>>(XL, Wq, bq, Wk, bk, Wv, bv, fcos, fsin, Qb, Kb, Vb);
    k3_attn<<<dim3(25, NH, TT), 256, 0, stream>>>(Qb, Kb, Vb, Ob);
    k4_out<<<dim3(SEQ / 64, DIM / 128), 256, 0, stream>>>(Ob, Wcbf, bc, out);
}

// Round 11
// 1196.910 us; speedup vs baseline: 1.6108x; 1.6108x over previous
//
#include <hip/hip_runtime.h>
#include <hip/hip_bf16.h>

// DeRA forward: x @ Wd^T -> qkv+rope -> attn -> (o @ (Wup*Wo)^T + Wup*bo)
// Shapes fixed: seq=12480 = 8 frames x (30*52=1560), DIM=3072, RANK=192, 4 heads x 48.

#define DIM 3072
#define RANK 192
#define NH 4
#define HD 48
#define CP 24           // pairs per head
#define TT 8
#define GW 52
#define SF 1560
#define SEQ 12480

typedef float f32x4 __attribute__((ext_vector_type(4)));
typedef short bf16x8 __attribute__((ext_vector_type(8)));

static __device__ __forceinline__ unsigned short f2bf(float f) {
    union { float f; unsigned int u; } v; v.f = f;
    unsigned int u = v.u;
    return (unsigned short)((u + 0x7FFFu + ((u >> 16) & 1u)) >> 16);  // RNE
}
static __device__ __forceinline__ ushort4 cvt4(float4 v) {
    ushort4 o; o.x = f2bf(v.x); o.y = f2bf(v.y); o.z = f2bf(v.z); o.w = f2bf(v.w);
    return o;
}

// ---------------- prep: Wc = Wup @ Wo (bf16), bc = Wup @ bo ----------------
__global__ __launch_bounds__(256) void prep_combine(
        const float* __restrict__ Wup, const float* __restrict__ Wo,
        const float* __restrict__ bo, unsigned short* __restrict__ Wcbf,
        float* __restrict__ bc) {
    int idx = blockIdx.x * 256 + threadIdx.x;
    if (idx >= DIM * RANK) return;
    int i = idx / RANK, j = idx % RANK;
    float s = 0.f;
    #pragma unroll 8
    for (int r = 0; r < RANK; ++r) s += Wup[i * RANK + r] * Wo[r * RANK + j];
    Wcbf[idx] = f2bf(s);
    if (j == 0) {
        float t = 0.f;
        for (int r = 0; r < RANK; ++r) t += Wup[i * RANK + r] * bo[r];
        bc[i] = t;
    }
}

__global__ __launch_bounds__(256) void prep_cvt(
        const float* __restrict__ src, unsigned short* __restrict__ dst, int n4) {
    int idx = blockIdx.x * 256 + threadIdx.x;
    if (idx >= n4) return;
    float4 v = reinterpret_cast<const float4*>(src)[idx];
    reinterpret_cast<ushort4*>(dst)[idx] = cvt4(v);
}

// ---------------- K1: XLbf = bf16(X @ Wd^T)  (bf16 MFMA) ----------------
// BM=64 BN=64 BK=64, 4 waves 2x2, wave tile 32x32
#define K1_LDA 72   // 64 + 8 pad bf16 -> row stride 144B (16B-aligned, ~2-way banks)
__global__ __launch_bounds__(256) void k1_down(
        const float* __restrict__ X, const unsigned short* __restrict__ Wd,
        unsigned short* __restrict__ XLbf) {
    __shared__ unsigned short As[64][K1_LDA];
    __shared__ unsigned short Bs[64][K1_LDA];
    int m0 = blockIdx.x * 64, n0 = blockIdx.y * 64;
    int tid = threadIdx.x;
    int lane = tid & 63, wv = tid >> 6;
    int wm = wv >> 1, wn = wv & 1;
    f32x4 acc[2][2] = {};
    for (int k0 = 0; k0 < DIM; k0 += 64) {
        #pragma unroll
        for (int i = 0; i < 4; ++i) {          // A: 64x64 f32 -> bf16
            int q = tid + 256 * i;
            int row = q >> 4, c = (q & 15) * 4;
            float4 v = *reinterpret_cast<const float4*>(&X[(size_t)(m0 + row) * DIM + k0 + c]);
            *reinterpret_cast<ushort4*>(&As[row][c]) = cvt4(v);
        }
        #pragma unroll
        for (int i = 0; i < 2; ++i) {          // B: 64x64 bf16 = 512 int4 loads
            int q = tid + 256 * i;
            int row = q >> 3, c = (q & 7) * 8;
            *reinterpret_cast<int4*>(&Bs[row][c]) =
                *reinterpret_cast<const int4*>(&Wd[(size_t)(n0 + row) * DIM + k0 + c]);
        }
        __syncthreads();
        #pragma unroll
        for (int kk = 0; kk < 64; kk += 32) {
            int kof = kk + (lane >> 4) * 8;
            bf16x8 a[2], b[2];
            #pragma unroll
            for (int i = 0; i < 2; ++i)
                a[i] = *reinterpret_cast<const bf16x8*>(&As[wm * 32 + i * 16 + (lane & 15)][kof]);
            #pragma unroll
            for (int j = 0; j < 2; ++j)
                b[j] = *reinterpret_cast<const bf16x8*>(&Bs[wn * 32 + j * 16 + (lane & 15)][kof]);
            #pragma unroll
            for (int i = 0; i < 2; ++i)
                #pragma unroll
                for (int j = 0; j < 2; ++j)
                    acc[i][j] = __builtin_amdgcn_mfma_f32_16x16x32_bf16(a[i], b[j], acc[i][j], 0, 0, 0);
        }
        __syncthreads();
    }
    #pragma unroll
    for (int i = 0; i < 2; ++i)
        #pragma unroll
        for (int j = 0; j < 2; ++j)
            #pragma unroll
            for (int r = 0; r < 4; ++r) {
                int row = m0 + wm * 32 + i * 16 + (lane >> 4) * 4 + r;
                int col = n0 + wn * 32 + j * 16 + (lane & 15);
                XLbf[(size_t)row * RANK + col] = f2bf(acc[i][j][r]);
            }
}

// ---------------- K2: QKV GEMM (bf16 MFMA) + bias + RoPE epilogue ----------------
// M=SEQ, N=576 (Wq||Wk||Wv), K=192 fully staged. BM=64 BN=64, 4 waves 2x2.
// A 64-col output tile never crosses a mat (192%64=0) or head (48%16=0) boundary.
#define K2_LD 200   // 192 + 8 pad
__global__ __launch_bounds__(256) void k2_qkv(
        const unsigned short* __restrict__ XLbf,
        const unsigned short* __restrict__ Wqbf, const unsigned short* __restrict__ Wkbf,
        const unsigned short* __restrict__ Wvbf,
        const float* __restrict__ bq, const float* __restrict__ bk,
        const float* __restrict__ bv,
        const float* __restrict__ fcos, const float* __restrict__ fsin,
        float* __restrict__ Q, float* __restrict__ Kb, float* __restrict__ Vb) {
    __shared__ unsigned short As[64][K2_LD];
    __shared__ unsigned short Bs[64][K2_LD];
    int m0 = blockIdx.x * 64, n0 = blockIdx.y * 64;
    int tid = threadIdx.x, lane = tid & 63, wv = tid >> 6;
    int wm = wv >> 1, wn = wv & 1;
    #pragma unroll
    for (int i2 = 0; i2 < 6; ++i2) {           // A: 64x192 bf16 = 1536 int4
        int q = tid + 256 * i2;
        int row = q / 24, c = (q % 24) * 8;
        *reinterpret_cast<int4*>(&As[row][c]) =
            *reinterpret_cast<const int4*>(&XLbf[(size_t)(m0 + row) * RANK + c]);
    }
    int mat = n0 / 192;                        // uniform per block
    int nw = n0 % 192;
    const unsigned short* W = (mat == 0) ? Wqbf : (mat == 1) ? Wkbf : Wvbf;
    #pragma unroll
    for (int i2 = 0; i2 < 6; ++i2) {           // B: 64x192 bf16 = 1536 int4
        int q = tid + 256 * i2;
        int row = q / 24, c = (q % 24) * 8;
        *reinterpret_cast<int4*>(&Bs[row][c]) =
            *reinterpret_cast<const int4*>(&W[(size_t)(nw + row) * RANK + c]);
    }
    __syncthreads();
    f32x4 acc[2][2] = {};
    #pragma unroll
    for (int kk = 0; kk < RANK; kk += 32) {
        int kof = kk + (lane >> 4) * 8;
        bf16x8 a[2], b[2];
        #pragma unroll
        for (int i = 0; i < 2; ++i)
            a[i] = *reinterpret_cast<const bf16x8*>(&As[wm * 32 + i * 16 + (lane & 15)][kof]);
        #pragma unroll
        for (int j = 0; j < 2; ++j)
            b[j] = *reinterpret_cast<const bf16x8*>(&Bs[wn * 32 + j * 16 + (lane & 15)][kof]);
        #pragma unroll
        for (int i = 0; i < 2; ++i)
            #pragma unroll
            for (int j = 0; j < 2; ++j)
                acc[i][j] = __builtin_amdgcn_mfma_f32_16x16x32_bf16(a[i], b[j], acc[i][j], 0, 0, 0);
    }
    // epilogue: bias + RoPE (pair exchange via shfl_xor(.,1): adjacent cols in adjacent lanes)
    const float* bias = (mat == 0) ? bq : (mat == 1) ? bk : bv;
    float* dst = (mat == 0) ? Q : (mat == 1) ? Kb : Vb;
    int c15 = lane & 15;
    #pragma unroll
    for (int j = 0; j < 2; ++j) {
        int cmod = nw + wn * 32 + j * 16 + c15;   // within-mat channel 0..191
        int head = cmod / 48, d = cmod % 48;
        int pp = d >> 1, oddf = d & 1;
        float bval = bias[cmod];
        bool dorope = (mat < 2) && (pp >= 8);     // uniform within each lane pair
        #pragma unroll
        for (int i = 0; i < 2; ++i) {
            #pragma unroll
            for (int r = 0; r < 4; ++r) {
                int pos = m0 + wm * 32 + i * 16 + (lane >> 4) * 4 + r;
                float av = acc[i][j][r] + bval;
                float pv = __shfl_xor(av, 1);     // partner channel value (unconditional)
                int f = pos / SF, pf = pos % SF;
                float outv = av;
                if (dorope) {
                    int idx = (pp < 16) ? (pf / GW) : (pf % GW);
                    float cc = fcos[idx * CP + pp];
                    float ss = fsin[idx * CP + pp];
                    outv = oddf ? (pv * ss + av * cc) : (av * cc - pv * ss);
                }
                dst[(((size_t)(f * NH + head)) * SF + pf) * HD + d] = outv;
            }
        }
    }
}

// ---------------- K3: flash attention, f32 VALU ----------------
// grid (qtile 25, head 4, frame 8), 256 thr: r4 = tid/16 (4 q-rows), c4 = tid%16.
__global__ __launch_bounds__(256) void k3_attn(
        const float* __restrict__ Q, const float* __restrict__ Kb,
        const float* __restrict__ Vb, float* __restrict__ O) {
    __shared__ float Qs[64][52];
    __shared__ float Ks[64][52];
    __shared__ float Vs[64][52];
    __shared__ float Pt[64][68];   // P transposed: [k][q-row]
    int qt = blockIdx.x, n = blockIdx.y, f = blockIdx.z;
    size_t hbase = ((size_t)(f * NH + n)) * SF * HD;
    int q0 = qt * 64;
    int tid = threadIdx.x;
    int r4 = tid >> 4, c4 = tid & 15;
    const float scale = 0.14433756729740643f;  // 48^-0.5
    #pragma unroll
    for (int i = 0; i < 3; ++i) {              // stage Q (scaled)
        int q = tid + 256 * i;
        int row = q / 12, c = (q % 12) * 4;
        float4 v = {0.f, 0.f, 0.f, 0.f};
        if (q0 + row < SF)
            v = *reinterpret_cast<const float4*>(&Q[hbase + (size_t)(q0 + row) * HD + c]);
        v.x *= scale; v.y *= scale; v.z *= scale; v.w *= scale;
        *reinterpret_cast<float4*>(&Qs[row][c]) = v;
    }
    float Oa[4][3] = {};
    float mrow[4] = {-1e30f, -1e30f, -1e30f, -1e30f};
    float lrow[4] = {0.f, 0.f, 0.f, 0.f};
    for (int kt = 0; kt < 25; ++kt) {
        int kbase = kt * 64;
        __syncthreads();                       // prev PV done (and Q staged, iter 0)
        #pragma unroll
        for (int i = 0; i < 3; ++i) {          // stage K,V
            int q = tid + 256 * i;
            int row = q / 12, c = (q % 12) * 4;
            float4 kv = {0.f, 0.f, 0.f, 0.f}, vv = {0.f, 0.f, 0.f, 0.f};
            if (kbase + row < SF) {
                kv = *reinterpret_cast<const float4*>(&Kb[hbase + (size_t)(kbase + row) * HD + c]);
                vv = *reinterpret_cast<const float4*>(&Vb[hbase + (size_t)(kbase + row) * HD + c]);
            }
            *reinterpret_cast<float4*>(&Ks[row][c]) = kv;
            *reinterpret_cast<float4*>(&Vs[row][c]) = vv;
        }
        __syncthreads();
        float S[4][4] = {};
        #pragma unroll
        for (int kk = 0; kk < HD; kk += 4) {
            float4 qv[4], kv[4];
            #pragma unroll
            for (int i = 0; i < 4; ++i) qv[i] = *reinterpret_cast<const float4*>(&Qs[r4 * 4 + i][kk]);
            #pragma unroll
            for (int j = 0; j < 4; ++j) kv[j] = *reinterpret_cast<const float4*>(&Ks[c4 + 16 * j][kk]);
            #pragma unroll
            for (int i = 0; i < 4; ++i)
                #pragma unroll
                for (int j = 0; j < 4; ++j)
                    S[i][j] += qv[i].x * kv[j].x + qv[i].y * kv[j].y
                             + qv[i].z * kv[j].z + qv[i].w * kv[j].w;
        }
        #pragma unroll
        for (int j = 0; j < 4; ++j)
            if (kbase + c4 + 16 * j >= SF) {
                S[0][j] = -1e30f; S[1][j] = -1e30f; S[2][j] = -1e30f; S[3][j] = -1e30f;
            }
        #pragma unroll
        for (int i = 0; i < 4; ++i) {
            float mx = fmaxf(fmaxf(S[i][0], S[i][1]), fmaxf(S[i][2], S[i][3]));
            #pragma unroll
            for (int d = 1; d < 16; d <<= 1) mx = fmaxf(mx, __shfl_xor(mx, d));
            float mn = fmaxf(mrow[i], mx);
            float alpha = __expf(mrow[i] - mn);
            float rs = 0.f;
            #pragma unroll
            for (int j = 0; j < 4; ++j) { S[i][j] = __expf(S[i][j] - mn); rs += S[i][j]; }
            #pragma unroll
            for (int d = 1; d < 16; d <<= 1) rs += __shfl_xor(rs, d);
            lrow[i] = lrow[i] * alpha + rs;
            mrow[i] = mn;
            Oa[i][0] *= alpha; Oa[i][1] *= alpha; Oa[i][2] *= alpha;
        }
        #pragma unroll
        for (int j = 0; j < 4; ++j) {
            float4 pv; pv.x = S[0][j]; pv.y = S[1][j]; pv.z = S[2][j]; pv.w = S[3][j];
            *reinterpret_cast<float4*>(&Pt[c4 + 16 * j][r4 * 4]) = pv;
        }
        __syncthreads();
        int vc = c4 * 3;
        #pragma unroll 8
        for (int k = 0; k < 64; ++k) {
            float4 pv = *reinterpret_cast<const float4*>(&Pt[k][r4 * 4]);
            float v0 = Vs[k][vc], v1 = Vs[k][vc + 1], v2 = Vs[k][vc + 2];
            Oa[0][0] += pv.x * v0; Oa[0][1] += pv.x * v1; Oa[0][2] += pv.x * v2;
            Oa[1][0] += pv.y * v0; Oa[1][1] += pv.y * v1; Oa[1][2] += pv.y * v2;
            Oa[2][0] += pv.z * v0; Oa[2][1] += pv.z * v1; Oa[2][2] += pv.z * v2;
            Oa[3][0] += pv.w * v0; Oa[3][1] += pv.w * v1; Oa[3][2] += pv.w * v2;
        }
    }
    #pragma unroll
    for (int i = 0; i < 4; ++i) {
        int row = q0 + r4 * 4 + i;
        if (row < SF) {
            float inv = 1.0f / lrow[i];
            size_t ob = ((size_t)(f * SF + row)) * RANK + n * HD + c4 * 3;
            O[ob] = Oa[i][0] * inv; O[ob + 1] = Oa[i][1] * inv; O[ob + 2] = Oa[i][2] * inv;
        }
    }
}

// ---------------- K4: out = O @ Wc^T + bc  (bf16 MFMA) ----------------
// BM=64 BN=128, K=192 fully staged; 4 waves 2x2, wave tile 32x64
#define K4_LD 200   // 192 + 8 pad bf16 -> 400B stride (16B aligned)
__global__ __launch_bounds__(256) void k4_out(
        const float* __restrict__ O, const unsigned short* __restrict__ Wc,
        const float* __restrict__ bc, float* __restrict__ out) {
    __shared__ unsigned short As[64][K4_LD];
    __shared__ unsigned short Bs[128][K4_LD];
    int m0 = blockIdx.x * 64, n0 = blockIdx.y * 128;
    int tid = threadIdx.x, lane = tid & 63, wv = tid >> 6;
    int wm = wv >> 1, wn = wv & 1;
    #pragma unroll
    for (int i = 0; i < 12; ++i) {             // A: 64x192 f32 -> bf16 (3072 float4)
        int q = tid + 256 * i;
        int row = q / 48, c = (q % 48) * 4;
        float4 v = *reinterpret_cast<const float4*>(&O[(size_t)(m0 + row) * RANK + c]);
        *reinterpret_cast<ushort4*>(&As[row][c]) = cvt4(v);
    }
    #pragma unroll
    for (int i = 0; i < 12; ++i) {             // B: 128x192 bf16 = 3072 int4 loads
        int q = tid + 256 * i;
        int row = q / 24, c = (q % 24) * 8;
        *reinterpret_cast<int4*>(&Bs[row][c]) =
            *reinterpret_cast<const int4*>(&Wc[(size_t)(n0 + row) * RANK + c]);
    }
    __syncthreads();
    f32x4 acc[2][4] = {};
    #pragma unroll
    for (int kk = 0; kk < RANK; kk += 32) {
        int kof = kk + (lane >> 4) * 8;
        bf16x8 a[2], b[4];
        #pragma unroll
        for (int i = 0; i < 2; ++i)
            a[i] = *reinterpret_cast<const bf16x8*>(&As[wm * 32 + i * 16 + (lane & 15)][kof]);
        #pragma unroll
        for (int j = 0; j < 4; ++j)
            b[j] = *reinterpret_cast<const bf16x8*>(&Bs[wn * 64 + j * 16 + (lane & 15)][kof]);
        #pragma unroll
        for (int i = 0; i < 2; ++i)
            #pragma unroll
            for (int j = 0; j < 4; ++j)
                acc[i][j] = __builtin_amdgcn_mfma_f32_16x16x32_bf16(a[i], b[j], acc[i][j], 0, 0, 0);
    }
    #pragma unroll
    for (int i = 0; i < 2; ++i)
        #pragma unroll
        for (int j = 0; j < 4; ++j) {
            int col = n0 + wn * 64 + j * 16 + (lane & 15);
            float bias = bc[col];
            #pragma unroll
            for (int r = 0; r < 4; ++r) {
                int row = m0 + wm * 32 + i * 16 + (lane >> 4) * 4 + r;
                out[(size_t)row * DIM + col] = acc[i][j][r] + bias;
            }
        }
}

extern "C" void kernel_launch(void* const* d_in, const int* in_sizes, int n_in,
                              void* d_out, int out_size, void* d_ws, size_t ws_size,
                              hipStream_t stream) {
    (void)in_sizes; (void)n_in; (void)out_size; (void)ws_size;
    const float* x    = (const float*)d_in[0];
    const float* fcos = (const float*)d_in[6];
    const float* fsin = (const float*)d_in[7];
    const float* Wd   = (const float*)d_in[8];
    const float* Wup  = (const float*)d_in[9];
    const float* Wq   = (const float*)d_in[10];
    const float* bq   = (const float*)d_in[11];
    const float* Wk   = (const float*)d_in[12];
    const float* bk   = (const float*)d_in[13];
    const float* Wv   = (const float*)d_in[14];
    const float* bv   = (const float*)d_in[15];
    const float* Wo   = (const float*)d_in[16];
    const float* bo   = (const float*)d_in[17];
    float* out = (float*)d_out;

    char* ws = (char*)d_ws;
    size_t off = 0;
    auto alloc = [&](size_t bytes) {
        char* p = ws + off;
        off += (bytes + 255) & ~(size_t)255;
        return p;
    };
    unsigned short* XLbf = (unsigned short*)alloc((size_t)SEQ * RANK * 2);
    float* Qb  = (float*)alloc((size_t)SEQ * RANK * 4);
    float* Kb  = (float*)alloc((size_t)SEQ * RANK * 4);
    float* Vb  = (float*)alloc((size_t)SEQ * RANK * 4);
    float* Ob  = (float*)alloc((size_t)SEQ * RANK * 4);
    unsigned short* Wdbf = (unsigned short*)alloc((size_t)RANK * DIM * 2);
    unsigned short* Wcbf = (unsigned short*)alloc((size_t)DIM * RANK * 2);
    float* bc = (float*)alloc((size_t)DIM * 4);
    unsigned short* Wqbf = (unsigned short*)alloc((size_t)RANK * RANK * 2);
    unsigned short* Wkbf = (unsigned short*)alloc((size_t)RANK * RANK * 2);
    unsigned short* Wvbf = (unsigned short*)alloc((size_t)RANK * RANK * 2);

    prep_combine<<<(DIM * RANK + 255) / 256, 256, 0, stream>>>(Wup, Wo, bo, Wcbf, bc);
    prep_cvt<<<(RANK * DIM / 4 + 255) / 256, 256, 0, stream>>>(Wd, Wdbf, RANK * DIM / 4);
    prep_cvt<<<(RANK * RANK / 4 + 255) / 256, 256, 0, stream>>>(Wq, Wqbf, RANK * RANK / 4);
    prep_cvt<<<(RANK * RANK / 4 + 255) / 256, 256, 0, stream>>>(Wk, Wkbf, RANK * RANK / 4);
    prep_cvt<<<(RANK * RANK / 4 + 255) / 256, 256, 0, stream>>>(Wv, Wvbf, RANK * RANK / 4);
    k1_down<<<dim3(SEQ / 64, RANK / 64), 256, 0, stream>>>(x, Wdbf, XLbf);
    k2_qkv<<<dim3(SEQ / 64, 576 / 64), 256, 0, stream>>>(
        XLbf, Wqbf, Wkbf, Wvbf, bq, bk, bv, fcos, fsin, Qb, Kb, Vb);
    k3_attn<<<dim3(25, NH, TT), 256, 0, stream>>>(Qb, Kb, Vb, Ob);
    k4_out<<<dim3(SEQ / 64, DIM / 128), 256, 0, stream>>>(Ob, Wcbf, bc, out);
}